// Round 11
// baseline (374.018 us; speedup 1.0000x reference)
//
#include <hip/hip_runtime.h>
#include <math.h>

// ---- problem constants ----
#define CIN  2048
#define NB   64               // batch
#define PPIX 196              // pixels per image
#define NPIX 12544
#define KZN  8                // K-slices (across blockIdx.y)
#define KSL  256              // k per slice
#define PXB  56               // pixels per gemv block (8 waves x 7)
#define PXW  7                // pixels per wave
#define NPB  (NPIX / PXB)     // 224 pixel-blocks

typedef float f32x4 __attribute__((ext_vector_type(4)));

// ---- kernel 1: h1 partial GEMV. grid (224 pixel-blocks, 8 k-slices). ----
// Block stages its W-slice [kz*256..+256)[64] f32 (64KB, contiguous in W1)
// into LDS via global_load_lds, then each wave computes 7 pixels x 256 k:
//   lane = output channel n; w via conflict-free ds_read_b32 (consecutive
//   4B across lanes); x via wave-uniform f32x4 loads (1 line/load, 4 steps
//   per 64B line, x read exactly once globally), 1-deep pipelined.
// No intra-block reduction: waves write h1part[kz][pix][n] directly.
__global__ __launch_bounds__(512, 4) void h1_gemv(
    const float* __restrict__ x, const float* __restrict__ W1,
    float* __restrict__ h1part)
{
    __shared__ float Wl[KSL * 64];       // 64 KB, [k][n], linear
    const int t    = threadIdx.x;        // 0..511
    const int wv   = t >> 6;             // wave 0..7
    const int lane = t & 63;             // = output channel n
    const int pb   = blockIdx.x;
    const int kz   = blockIdx.y;

    // stage W slice: wave wv DMAs 8 x 1KB chunks (fire-and-forget)
    {
        const char* wsrc = (const char*)(W1 + (size_t)kz * KSL * 64);
        char* wdst = (char*)Wl;
#pragma unroll
        for (int j = 0; j < 8; ++j)
            __builtin_amdgcn_global_load_lds(
                (const float*)(wsrc + (wv * 8 + j) * 1024 + lane * 16),
                (float*)(wdst + (wv * 8 + j) * 1024), 16, 0, 0);
    }
    __syncthreads();                     // drains vmcnt: W resident

    const int pix0 = pb * PXB + wv * PXW;
    const float* xr0 = x + (size_t)pix0 * CIN + kz * KSL;  // wave-uniform

    float acc[PXW];
#pragma unroll
    for (int p = 0; p < PXW; ++p) acc[p] = 0.f;

    f32x4 xc[PXW], xn[PXW];
#pragma unroll
    for (int p = 0; p < PXW; ++p) xc[p] = *(const f32x4*)(xr0 + (size_t)p * CIN);
#pragma unroll
    for (int p = 0; p < PXW; ++p) xn[p] = xc[p];

    for (int kb = 0; kb < KSL / 4; ++kb) {   // 64 iters
        if (kb < KSL / 4 - 1) {              // prefetch next 4 k per pixel
#pragma unroll
            for (int p = 0; p < PXW; ++p)
                xn[p] = *(const f32x4*)(xr0 + (size_t)p * CIN + (kb + 1) * 4);
        }
        const int k0 = kb * 4;
        const float w0 = Wl[(k0 + 0) * 64 + lane];   // conflict-free b32
        const float w1 = Wl[(k0 + 1) * 64 + lane];
        const float w2 = Wl[(k0 + 2) * 64 + lane];
        const float w3 = Wl[(k0 + 3) * 64 + lane];
#pragma unroll
        for (int p = 0; p < PXW; ++p)
            acc[p] = fmaf(xc[p][3], w3, fmaf(xc[p][2], w2,
                     fmaf(xc[p][1], w1, fmaf(xc[p][0], w0, acc[p]))));
#pragma unroll
        for (int p = 0; p < PXW; ++p) xc[p] = xn[p];
    }
#pragma unroll
    for (int p = 0; p < PXW; ++p)
        h1part[((size_t)kz * NPIX + pix0 + p) * 64 + lane] = acc[p];
}

// ---- kernel 2: reduce K-partials + MLP tail -> a. 784 blocks x 256. ----
__global__ __launch_bounds__(256) void attn_tail(
    const float* __restrict__ h1part, const float* __restrict__ b1,
    const float* __restrict__ W2, const float* __restrict__ b2,
    const float* __restrict__ W3, const float* __restrict__ b3,
    const float* __restrict__ W4, const float* __restrict__ b4,
    float* __restrict__ a_out)
{
    __shared__ float h1s[16][72];        // row stride 288B: 16B-aligned cols
    __shared__ float h2s[16][16];
    __shared__ float h3s[16][8];
    const int t = threadIdx.x, blk = blockIdx.x;
    const int p = t >> 4, j = t & 15;
    const int pix = blk * 16 + p;

    // reduce 8 K-partials (+bias, relu): thread owns 4 channels of 1 pixel
    f32x4 s = *(const f32x4*)(b1 + j * 4);
#pragma unroll
    for (int kz = 0; kz < KZN; ++kz)
        s += *(const f32x4*)(h1part + ((size_t)kz * NPIX + pix) * 64 + j * 4);
    f32x4 hv;
#pragma unroll
    for (int i = 0; i < 4; ++i) hv[i] = fmaxf(s[i], 0.f);
    *(f32x4*)&h1s[p][j * 4] = hv;
    __syncthreads();

    // layer 2: 16 threads/pixel
    {
        float v = b2[j];
#pragma unroll
        for (int k = 0; k < 64; ++k) v = fmaf(h1s[p][k], W2[k * 16 + j], v);
        h2s[p][j] = fmaxf(v, 0.f);
    }
    __syncthreads();
    if (t < 128) {                       // layer 3: 8 threads/pixel
        const int p3 = t >> 3, j3 = t & 7;
        float v = b3[j3];
#pragma unroll
        for (int k = 0; k < 16; ++k) v = fmaf(h2s[p3][k], W3[k * 8 + j3], v);
        h3s[p3][j3] = fmaxf(v, 0.f);
    }
    __syncthreads();
    if (t < 16) {                        // layer 4 + sigmoid
        float z = b4[0];
#pragma unroll
        for (int k = 0; k < 8; ++k) z = fmaf(h3s[t][k], W4[k], z);
        a_out[blk * 16 + t] = 1.f / (1.f + expf(-z));
    }
}

// ---- kernel 3: partial weighted sums (round-0 proven). grid (2,64,2). ----
__global__ __launch_bounds__(256) void gap_partial(
    const float* __restrict__ x, const float* __restrict__ a,
    float* __restrict__ part)
{
    const int b  = blockIdx.y;
    const int pz = blockIdx.z;                       // 0..1 (98 pixels each)
    const int c0 = (blockIdx.x * 256 + threadIdx.x) * 4;
    const float* xb = x + ((size_t)b * PPIX + pz * 98) * CIN + c0;
    const float* ab = a + b * PPIX + pz * 98;

    float4 s0 = {0, 0, 0, 0}, s1 = {0, 0, 0, 0};
#pragma unroll 4
    for (int p = 0; p < 98; p += 2) {
        const float a0 = ab[p], a1 = ab[p + 1];
        const float4 v0 = *(const float4*)(xb + (size_t)p * CIN);
        const float4 v1 = *(const float4*)(xb + (size_t)(p + 1) * CIN);
        s0.x = fmaf(a0, v0.x, s0.x); s0.y = fmaf(a0, v0.y, s0.y);
        s0.z = fmaf(a0, v0.z, s0.z); s0.w = fmaf(a0, v0.w, s0.w);
        s1.x = fmaf(a1, v1.x, s1.x); s1.y = fmaf(a1, v1.y, s1.y);
        s1.z = fmaf(a1, v1.z, s1.z); s1.w = fmaf(a1, v1.w, s1.w);
    }
    float4 r;
    r.x = s0.x + s1.x; r.y = s0.y + s1.y; r.z = s0.z + s1.z; r.w = s0.w + s1.w;
    *(float4*)(part + ((size_t)pz * NB + b) * CIN + c0) = r;
}

// ---- kernel 4: finalize (round-0 proven). grid 64, block 512. ----
__global__ __launch_bounds__(512) void gap_final(
    const float* __restrict__ a, const float* __restrict__ part,
    float* __restrict__ out)
{
    __shared__ float red[512];
    const int b = blockIdx.x, t = threadIdx.x;
    red[t] = (t < PPIX) ? a[b * PPIX + t] : 0.f;
    __syncthreads();
#pragma unroll
    for (int s = 256; s > 0; s >>= 1) {
        if (t < s) red[t] += red[t + s];
        __syncthreads();
    }
    const float inv = 1.f / red[0];
    const int c0 = t * 4;
    const float4 p0 = *(const float4*)(part + ((size_t)0 * NB + b) * CIN + c0);
    const float4 p1 = *(const float4*)(part + ((size_t)1 * NB + b) * CIN + c0);
    float4 r;
    r.x = (p0.x + p1.x) * inv; r.y = (p0.y + p1.y) * inv;
    r.z = (p0.z + p1.z) * inv; r.w = (p0.w + p1.w) * inv;
    *(float4*)(out + (size_t)b * CIN + c0) = r;
}

extern "C" void kernel_launch(void* const* d_in, const int* in_sizes, int n_in,
                              void* d_out, int out_size, void* d_ws, size_t ws_size,
                              hipStream_t stream)
{
    const float* x  = (const float*)d_in[0];
    const float* W1 = (const float*)d_in[1];
    const float* b1 = (const float*)d_in[2];
    const float* W2 = (const float*)d_in[3];
    const float* b2 = (const float*)d_in[4];
    const float* W3 = (const float*)d_in[5];
    const float* b3 = (const float*)d_in[6];
    const float* W4 = (const float*)d_in[7];
    const float* b4 = (const float*)d_in[8];
    float* out = (float*)d_out;

    // ws layout: a f32 [12544] @256KB | h1part f32 [8][12544][64] @1MB
    //            (24.5MB) | part f32 [2][64][2048] @28MB (1MB). Total ~29MB.
    float* a      = (float*)((char*)d_ws + (256 << 10));
    float* h1part = (float*)((char*)d_ws + (1 << 20));
    float* part   = (float*)((char*)d_ws + (28u << 20));

    h1_gemv<<<dim3(NPB, KZN), 512, 0, stream>>>(x, W1, h1part);
    attn_tail<<<NPIX / 16, 256, 0, stream>>>(h1part, b1, W2, b2, W3, b3, W4, b4, a);
    gap_partial<<<dim3(2, NB, 2), 256, 0, stream>>>(x, a, part);
    gap_final<<<NB, 512, 0, stream>>>(a, part, out);
}